// Round 9
// baseline (166.727 us; speedup 1.0000x reference)
//
#include <hip/hip_runtime.h>

#define NV 1448
#define JD 4344    // 3*NV
#define CC 256
#define BB 64
#define QQ 128     // 2*BB
#define QCOLS 362  // NV/4, columns per chamfer block
#define NROW (2 * BB * NV)  // 185344 row-slots (dir x b x row)

// ---------------------------------------------------------------------------
// K1: global average pool over H*W=64 -> latQ[q][c], q = t*64+b
// ---------------------------------------------------------------------------
__global__ __launch_bounds__(256) void pool_kernel(const float* __restrict__ inp,
                                                   const float* __restrict__ tgt,
                                                   float* __restrict__ latQ) {
    int gid  = blockIdx.x * 256 + threadIdx.x;
    int lane = gid & 15;
    int row  = gid >> 4;                          // (t,b,c) flat, 32768 rows
    if (row >= 2 * BB * CC) return;
    int t  = row >> 14;                           // BB*CC = 16384
    int bc = row & 16383;
    const float* src = (t ? tgt : inp) + (size_t)bc * 64;
    float4 v = reinterpret_cast<const float4*>(src)[lane];
    float s = (v.x + v.y) + (v.z + v.w);
    s += __shfl_xor(s, 1);
    s += __shfl_xor(s, 2);
    s += __shfl_xor(s, 4);
    s += __shfl_xor(s, 8);
    if (lane == 0) {
        int b = bc >> 8, c = bc & 255;
        latQ[(size_t)(t * 64 + b) * CC + c] = s * (1.0f / 64.0f);
    }
}

// ---------------------------------------------------------------------------
// K2: decode GEMM, LDS-FREE. grid (136 j-tiles, 2 L) x 512 thr.
// thread: jl = tid&7 -> 4 j's at j0 = jt*32 + jl*4; qg = tid>>3 -> 2 q's.
// Reads delta rows (16B chunks, L2-resident after first pass) and lat rows
// (L1-resident, wave-broadcast) directly from global; 64 fma per 12 loads.
// No LDS, no barriers.
// ---------------------------------------------------------------------------
__global__ __launch_bounds__(512) void decode_kernel(const float* __restrict__ latQ,
                                                     const float* __restrict__ muL,
                                                     const float* __restrict__ deltaL,
                                                     const float* __restrict__ muR,
                                                     const float* __restrict__ deltaR,
                                                     const int* __restrict__ labels,
                                                     float* __restrict__ pts3) {
    const int jt = blockIdx.x;                 // 0..135
    const int L  = blockIdx.y;
    const float* __restrict__ delta = L ? deltaR : deltaL;
    const float* __restrict__ mu    = L ? muR : muL;
    const int tid = threadIdx.x;
    const int jl  = tid & 7;
    const int qg  = tid >> 3;                  // 0..63
    const int j0  = jt * 32 + jl * 4;
    const bool jok = j0 < JD;                  // JD%4==0 -> full quad or none
    const int q0  = qg * 2;

    const float* __restrict__ dA = delta + (size_t)(jok ? j0 : 0) * CC;
    const float* __restrict__ l0 = latQ + (size_t)q0 * CC;
    const float* __restrict__ l1 = l0 + CC;

    float acc[4][2];
#pragma unroll
    for (int u = 0; u < 4; ++u) { acc[u][0] = 0.f; acc[u][1] = 0.f; }

    for (int k = 0; k < CC; k += 8) {
        float4 b0a = *reinterpret_cast<const float4*>(l0 + k);
        float4 b0b = *reinterpret_cast<const float4*>(l0 + k + 4);
        float4 b1a = *reinterpret_cast<const float4*>(l1 + k);
        float4 b1b = *reinterpret_cast<const float4*>(l1 + k + 4);
#pragma unroll
        for (int u = 0; u < 4; ++u) {
            float4 aa = *reinterpret_cast<const float4*>(dA + u * CC + k);
            float4 ab = *reinterpret_cast<const float4*>(dA + u * CC + k + 4);
            acc[u][0] = fmaf(aa.x, b0a.x, fmaf(aa.y, b0a.y, fmaf(aa.z, b0a.z, fmaf(aa.w, b0a.w, acc[u][0]))));
            acc[u][0] = fmaf(ab.x, b0b.x, fmaf(ab.y, b0b.y, fmaf(ab.z, b0b.z, fmaf(ab.w, b0b.w, acc[u][0]))));
            acc[u][1] = fmaf(aa.x, b1a.x, fmaf(aa.y, b1a.y, fmaf(aa.z, b1a.z, fmaf(aa.w, b1a.w, acc[u][1]))));
            acc[u][1] = fmaf(ab.x, b1b.x, fmaf(ab.y, b1b.y, fmaf(ab.z, b1b.z, fmaf(ab.w, b1b.w, acc[u][1]))));
        }
    }

    if (jok) {
        float4 mv = *reinterpret_cast<const float4*>(mu + j0);
#pragma unroll
        for (int v = 0; v < 2; ++v) {
            int q = q0 + v;
            int b = q & 63;
            if (labels[b] == L) {
                float4 o = make_float4(acc[0][v] + mv.x, acc[1][v] + mv.y,
                                       acc[2][v] + mv.z, acc[3][v] + mv.w);
                *reinterpret_cast<float4*>(pts3 + (size_t)q * JD + j0) = o;
            }
        }
    }
}

// ---------------------------------------------------------------------------
// K2b: pack points as float4(x,y,z,|p|^2)
// ---------------------------------------------------------------------------
__global__ __launch_bounds__(256) void pack_kernel(const float* __restrict__ pts3,
                                                   float4* __restrict__ pts4) {
    int gid = blockIdx.x * 256 + threadIdx.x;   // QQ*NV = 185344 = 724*256
    if (gid >= QQ * NV) return;
    int tb = gid / NV;
    int n  = gid - tb * NV;
    const float* p = pts3 + (size_t)tb * JD + n * 3;
    float x = p[0], y = p[1], z = p[2];
    pts4[gid] = make_float4(x, y, z, fmaf(x, x, fmaf(y, y, z * z)));
}

// ---------------------------------------------------------------------------
// K3: chamfer partial row-mins (R3-proven structure) + guaranteed v_min3_f32.
// grid (chunk 0..2, b 0..63, z 0..7: dir=z>>2, q=z&3); 1536 blocks.
// B quarter staged in LDS as (-2x,-2y,-2z,|b|^2); min over
// d' = fma(bx,ax, fma(by,ay, fma(bz,az, bw))); |a|^2 added at epilogue.
// 2 rows/thread; 7 VALU per 2 pairs.
// ---------------------------------------------------------------------------
__global__ __launch_bounds__(256) void chamfer_kernel(const float4* __restrict__ pts4,
                                                      float* __restrict__ pmin) {
    const int chunk = blockIdx.x;
    const int b     = blockIdx.y;
    const int dir   = blockIdx.z >> 2;
    const int q     = blockIdx.z & 3;
    const float4* __restrict__ Ap = pts4 + (size_t)(dir * BB + b) * NV;
    const float4* __restrict__ Bp = pts4 + (size_t)((1 - dir) * BB + b) * NV + q * QCOLS;

    __shared__ float4 Bs[QCOLS];
    const int tid = threadIdx.x;
    for (int i = tid; i < QCOLS; i += 256) {
        float4 v = Bp[i];
        Bs[i] = make_float4(-2.f * v.x, -2.f * v.y, -2.f * v.z, v.w);
    }
    __syncthreads();

    int r0 = chunk * 512 + tid;
    int r1 = r0 + 256;
    float4 a0 = (r0 < NV) ? Ap[r0] : make_float4(0.f, 0.f, 0.f, 0.f);
    float4 a1 = (r1 < NV) ? Ap[r1] : make_float4(0.f, 0.f, 0.f, 0.f);
    float m0 = 1e30f, m1 = 1e30f;

#pragma unroll 2
    for (int m = 0; m < QCOLS; m += 2) {
        float4 b0 = Bs[m];
        float4 b1 = Bs[m + 1];
        float d00 = fmaf(b0.x, a0.x, fmaf(b0.y, a0.y, fmaf(b0.z, a0.z, b0.w)));
        float d01 = fmaf(b1.x, a0.x, fmaf(b1.y, a0.y, fmaf(b1.z, a0.z, b1.w)));
        asm("v_min3_f32 %0, %0, %1, %2" : "+v"(m0) : "v"(d00), "v"(d01));
        float d10 = fmaf(b0.x, a1.x, fmaf(b0.y, a1.y, fmaf(b0.z, a1.z, b0.w)));
        float d11 = fmaf(b1.x, a1.x, fmaf(b1.y, a1.y, fmaf(b1.z, a1.z, b1.w)));
        asm("v_min3_f32 %0, %0, %1, %2" : "+v"(m1) : "v"(d10), "v"(d11));
    }

    size_t base = (size_t)q * NROW + (size_t)(dir * BB + b) * NV;
    if (r0 < NV) pmin[base + r0] = m0 + a0.w;     // restore |a|^2
    if (r1 < NV) pmin[base + r1] = m1 + a1.w;
}

// ---------------------------------------------------------------------------
// K3b: combine 4 quarter-mins, sqrt, per-block sums. 362 blocks x 256 x 2.
// ---------------------------------------------------------------------------
__global__ __launch_bounds__(256) void combine_kernel(const float* __restrict__ pmin,
                                                      float* __restrict__ partials) {
    int g0 = blockIdx.x * 512 + threadIdx.x;
    int g1 = g0 + 256;
    float v0 = fminf(fminf(pmin[g0], pmin[g0 + NROW]),
                     fminf(pmin[g0 + 2 * NROW], pmin[g0 + 3 * NROW]));
    float v1 = fminf(fminf(pmin[g1], pmin[g1 + NROW]),
                     fminf(pmin[g1 + 2 * NROW], pmin[g1 + 3 * NROW]));
    float s = sqrtf(fmaxf(v0, 1e-12f)) + sqrtf(fmaxf(v1, 1e-12f));
    s += __shfl_xor(s, 1);
    s += __shfl_xor(s, 2);
    s += __shfl_xor(s, 4);
    s += __shfl_xor(s, 8);
    s += __shfl_xor(s, 16);
    s += __shfl_xor(s, 32);
    __shared__ float wsum[4];
    if ((threadIdx.x & 63) == 0) wsum[threadIdx.x >> 6] = s;
    __syncthreads();
    if (threadIdx.x == 0)
        partials[blockIdx.x] = wsum[0] + wsum[1] + wsum[2] + wsum[3];
}

// ---------------------------------------------------------------------------
// K4: final reduce of 362 partials -> scalar
// ---------------------------------------------------------------------------
__global__ __launch_bounds__(256) void finalize_kernel(const float* __restrict__ partials,
                                                       float* __restrict__ out) {
    int tid = threadIdx.x;
    float s = 0.f;
    for (int i = tid; i < 362; i += 256) s += partials[i];
    s += __shfl_xor(s, 1);
    s += __shfl_xor(s, 2);
    s += __shfl_xor(s, 4);
    s += __shfl_xor(s, 8);
    s += __shfl_xor(s, 16);
    s += __shfl_xor(s, 32);
    __shared__ float wsum[4];
    if ((tid & 63) == 0) wsum[tid >> 6] = s;
    __syncthreads();
    if (tid == 0)
        out[0] = (wsum[0] + wsum[1] + wsum[2] + wsum[3]) * (1.0f / (64.0f * 1448.0f));
}

extern "C" void kernel_launch(void* const* d_in, const int* in_sizes, int n_in,
                              void* d_out, int out_size, void* d_ws, size_t ws_size,
                              hipStream_t stream) {
    const float* inp    = (const float*)d_in[0];
    const float* tgt    = (const float*)d_in[1];
    const int*   labels = (const int*)d_in[2];
    const float* muL    = (const float*)d_in[3];
    const float* deltaL = (const float*)d_in[4];
    const float* muR    = (const float*)d_in[5];
    const float* deltaR = (const float*)d_in[6];
    float* out = (float*)d_out;

    char* ws = (char*)d_ws;
    float*  latQ = (float*)ws;                                   // 128*256*4 = 131072 B
    float*  pts3 = (float*)(ws + 131072);                        // 128*4344*4 = 2224128 B
    float4* pts4 = (float4*)(ws + 131072 + 2224128);             // 185344*16 = 2965504 B
    float*  pmin = (float*)(ws + 131072 + 2224128 + 2965504);    // 4*185344*4 = 2965504 B
    float*  partials = latQ;   // latQ dead after decode; 362*4 B

    hipLaunchKernelGGL(pool_kernel, dim3(2048), dim3(256), 0, stream, inp, tgt, latQ);
    hipLaunchKernelGGL(decode_kernel, dim3(136, 2), dim3(512), 0, stream,
                       latQ, muL, deltaL, muR, deltaR, labels, pts3);
    hipLaunchKernelGGL(pack_kernel, dim3((QQ * NV + 255) / 256), dim3(256), 0, stream,
                       pts3, pts4);
    hipLaunchKernelGGL(chamfer_kernel, dim3(3, 64, 8), dim3(256), 0, stream,
                       pts4, pmin);
    hipLaunchKernelGGL(combine_kernel, dim3(362), dim3(256), 0, stream, pmin, partials);
    hipLaunchKernelGGL(finalize_kernel, dim3(1), dim3(256), 0, stream, partials, out);
}

// Round 10
// 65.732 us; speedup vs baseline: 2.5365x; 2.5365x over previous
//
#include <hip/hip_runtime.h>

#define NV 1448
#define JD 4344    // 3*NV
#define CC 256
#define BB 64
#define QQ 128     // 2*BB
#define QCOLS 362  // NV/4, columns per chamfer block
#define NROW (2 * BB * NV)  // 185344 row-slots (dir x b x row)

// ---------------------------------------------------------------------------
// K1: global average pool over H*W=64 -> latT[c][q], q = t*64+b.
// Thread 0 zeroes the combine accumulator (no memset node needed).
// ---------------------------------------------------------------------------
__global__ __launch_bounds__(256) void pool_kernel(const float* __restrict__ inp,
                                                   const float* __restrict__ tgt,
                                                   float* __restrict__ latT,
                                                   unsigned long long* __restrict__ acc) {
    int gid  = blockIdx.x * 256 + threadIdx.x;
    if (gid == 0) { acc[0] = 0ull; acc[1] = 0ull; }
    int lane = gid & 15;
    int row  = gid >> 4;                          // (t,b,c) flat, 32768 rows
    if (row >= 2 * BB * CC) return;
    int t  = row >> 14;                           // BB*CC = 16384
    int bc = row & 16383;
    const float* src = (t ? tgt : inp) + (size_t)bc * 64;
    float4 v = reinterpret_cast<const float4*>(src)[lane];
    float s = (v.x + v.y) + (v.z + v.w);
    s += __shfl_xor(s, 1);
    s += __shfl_xor(s, 2);
    s += __shfl_xor(s, 4);
    s += __shfl_xor(s, 8);
    if (lane == 0) {
        int b = bc >> 8, c = bc & 255;
        latT[c * QQ + t * BB + b] = s * (1.0f / 64.0f);
    }
}

// ---------------------------------------------------------------------------
// K2: decode GEMM (R5 LDS version — best measured), 4j x 4q register blocking.
// grid (68 jt, 2 L, 2 qh) x 256 thr.
// ---------------------------------------------------------------------------
__global__ __launch_bounds__(256) void decode_kernel(const float* __restrict__ latT,
                                                     const float* __restrict__ muL,
                                                     const float* __restrict__ deltaL,
                                                     const float* __restrict__ muR,
                                                     const float* __restrict__ deltaR,
                                                     const int* __restrict__ labels,
                                                     float* __restrict__ pts3) {
    const int jt = blockIdx.x;                 // 68 tiles of 64 j
    const int L  = blockIdx.y;
    const int qh = blockIdx.z;                 // q half: 64 q's
    const float* __restrict__ delta = L ? deltaR : deltaL;
    const float* __restrict__ mu    = L ? muR : muL;
    const int j0  = jt * 64;
    const int tid = threadIdx.x;
    const int jl  = tid & 15;
    const int qg  = tid >> 4;                  // 0..15

    __shared__ float AsT[32][64];              // [k][j]
    __shared__ float Bs[32][64];               // [k][q]

    float acc[4][4];
#pragma unroll
    for (int u = 0; u < 4; ++u)
#pragma unroll
        for (int v = 0; v < 4; ++v) acc[u][v] = 0.f;

    const int sj = tid & 63;                   // stage: j-lane
    const int sk = (tid >> 6) * 8;             // stage: k-base (0,8,16,24)
    const float4* latT4 = reinterpret_cast<const float4*>(latT);

    for (int kc = 0; kc < CC; kc += 32) {
        __syncthreads();
        {   // stage AsT: 64 j x 32 k
            int j = j0 + sj;
            float4 v0 = make_float4(0.f, 0.f, 0.f, 0.f), v1 = v0;
            if (j < JD) {
                const float4* dp = reinterpret_cast<const float4*>(delta + (size_t)j * CC + kc + sk);
                v0 = dp[0]; v1 = dp[1];
            }
            AsT[sk + 0][sj] = v0.x; AsT[sk + 1][sj] = v0.y;
            AsT[sk + 2][sj] = v0.z; AsT[sk + 3][sj] = v0.w;
            AsT[sk + 4][sj] = v1.x; AsT[sk + 5][sj] = v1.y;
            AsT[sk + 6][sj] = v1.z; AsT[sk + 7][sj] = v1.w;
        }
        {   // stage Bs: 32 k x 64 q = 512 float4, 2 per thread
            int k  = tid >> 4;                 // 0..15
            int qi = tid & 15;
            reinterpret_cast<float4*>(&Bs[k][0])[qi]      = latT4[(size_t)(kc + k) * 32 + qh * 16 + qi];
            reinterpret_cast<float4*>(&Bs[k + 16][0])[qi] = latT4[(size_t)(kc + k + 16) * 32 + qh * 16 + qi];
        }
        __syncthreads();

#pragma unroll
        for (int k4 = 0; k4 < 32; k4 += 4) {
#pragma unroll
            for (int kk = 0; kk < 4; ++kk) {
                float4 a = *reinterpret_cast<const float4*>(&AsT[k4 + kk][jl * 4]);
                float4 b = *reinterpret_cast<const float4*>(&Bs[k4 + kk][qg * 4]);
                float av[4] = {a.x, a.y, a.z, a.w};
                float bv[4] = {b.x, b.y, b.z, b.w};
#pragma unroll
                for (int u = 0; u < 4; ++u)
#pragma unroll
                    for (int v = 0; v < 4; ++v)
                        acc[u][v] = fmaf(av[u], bv[v], acc[u][v]);
            }
        }
    }

    int j = j0 + jl * 4;
    if (j < JD) {
        float4 m = *reinterpret_cast<const float4*>(mu + j);
        float mu4[4] = {m.x, m.y, m.z, m.w};
#pragma unroll
        for (int v = 0; v < 4; ++v) {
            int q = qh * 64 + qg * 4 + v;
            int b = q & 63;
            if (labels[b] == L) {
                float4 o = make_float4(acc[0][v] + mu4[0], acc[1][v] + mu4[1],
                                       acc[2][v] + mu4[2], acc[3][v] + mu4[3]);
                *reinterpret_cast<float4*>(pts3 + (size_t)q * JD + j) = o;
            }
        }
    }
}

// ---------------------------------------------------------------------------
// K2b: pack points as float4(x,y,z,|p|^2)
// ---------------------------------------------------------------------------
__global__ __launch_bounds__(256) void pack_kernel(const float* __restrict__ pts3,
                                                   float4* __restrict__ pts4) {
    int gid = blockIdx.x * 256 + threadIdx.x;   // QQ*NV = 185344 = 724*256
    if (gid >= QQ * NV) return;
    int tb = gid / NV;
    int n  = gid - tb * NV;
    const float* p = pts3 + (size_t)tb * JD + n * 3;
    float x = p[0], y = p[1], z = p[2];
    pts4[gid] = make_float4(x, y, z, fmaf(x, x, fmaf(y, y, z * z)));
}

// ---------------------------------------------------------------------------
// K3: chamfer partial row-mins (R9: forced v_min3_f32 — the proven win).
// grid (chunk 0..2, b 0..63, z 0..7: dir=z>>2, q=z&3); 1536 blocks.
// ---------------------------------------------------------------------------
__global__ __launch_bounds__(256) void chamfer_kernel(const float4* __restrict__ pts4,
                                                      float* __restrict__ pmin) {
    const int chunk = blockIdx.x;
    const int b     = blockIdx.y;
    const int dir   = blockIdx.z >> 2;
    const int q     = blockIdx.z & 3;
    const float4* __restrict__ Ap = pts4 + (size_t)(dir * BB + b) * NV;
    const float4* __restrict__ Bp = pts4 + (size_t)((1 - dir) * BB + b) * NV + q * QCOLS;

    __shared__ float4 Bs[QCOLS];
    const int tid = threadIdx.x;
    for (int i = tid; i < QCOLS; i += 256) {
        float4 v = Bp[i];
        Bs[i] = make_float4(-2.f * v.x, -2.f * v.y, -2.f * v.z, v.w);
    }
    __syncthreads();

    int r0 = chunk * 512 + tid;
    int r1 = r0 + 256;
    float4 a0 = (r0 < NV) ? Ap[r0] : make_float4(0.f, 0.f, 0.f, 0.f);
    float4 a1 = (r1 < NV) ? Ap[r1] : make_float4(0.f, 0.f, 0.f, 0.f);
    float m0 = 1e30f, m1 = 1e30f;

#pragma unroll 2
    for (int m = 0; m < QCOLS; m += 2) {
        float4 b0 = Bs[m];
        float4 b1 = Bs[m + 1];
        float d00 = fmaf(b0.x, a0.x, fmaf(b0.y, a0.y, fmaf(b0.z, a0.z, b0.w)));
        float d01 = fmaf(b1.x, a0.x, fmaf(b1.y, a0.y, fmaf(b1.z, a0.z, b1.w)));
        asm("v_min3_f32 %0, %0, %1, %2" : "+v"(m0) : "v"(d00), "v"(d01));
        float d10 = fmaf(b0.x, a1.x, fmaf(b0.y, a1.y, fmaf(b0.z, a1.z, b0.w)));
        float d11 = fmaf(b1.x, a1.x, fmaf(b1.y, a1.y, fmaf(b1.z, a1.z, b1.w)));
        asm("v_min3_f32 %0, %0, %1, %2" : "+v"(m1) : "v"(d10), "v"(d11));
    }

    size_t base = (size_t)q * NROW + (size_t)(dir * BB + b) * NV;
    if (r0 < NV) pmin[base + r0] = m0 + a0.w;     // restore |a|^2
    if (r1 < NV) pmin[base + r1] = m1 + a1.w;
}

// ---------------------------------------------------------------------------
// K3b: combine 4 quarter-mins, sqrt, block sums -> exact fixed-point atomic
// accumulate (order-independent => deterministic); last block writes out.
// 362 blocks x 256 thr x 2 rows = 185344 rows exactly.
// ---------------------------------------------------------------------------
__global__ __launch_bounds__(256) void combine_kernel(const float* __restrict__ pmin,
                                                      unsigned long long* __restrict__ acc,
                                                      float* __restrict__ out) {
    int g0 = blockIdx.x * 512 + threadIdx.x;
    int g1 = g0 + 256;
    float v0 = fminf(fminf(pmin[g0], pmin[g0 + NROW]),
                     fminf(pmin[g0 + 2 * NROW], pmin[g0 + 3 * NROW]));
    float v1 = fminf(fminf(pmin[g1], pmin[g1 + NROW]),
                     fminf(pmin[g1 + 2 * NROW], pmin[g1 + 3 * NROW]));
    float s = sqrtf(fmaxf(v0, 1e-12f)) + sqrtf(fmaxf(v1, 1e-12f));
    s += __shfl_xor(s, 1);
    s += __shfl_xor(s, 2);
    s += __shfl_xor(s, 4);
    s += __shfl_xor(s, 8);
    s += __shfl_xor(s, 16);
    s += __shfl_xor(s, 32);
    __shared__ float wsum[4];
    if ((threadIdx.x & 63) == 0) wsum[threadIdx.x >> 6] = s;
    __syncthreads();
    if (threadIdx.x == 0) {
        float bs = wsum[0] + wsum[1] + wsum[2] + wsum[3];
        unsigned long long qv = (unsigned long long)((double)bs * 16777216.0); // 2^24 fixed pt
        atomicAdd(acc, qv);
        __threadfence();
        unsigned long long done = atomicAdd(acc + 1, 1ull);
        if (done == 361) {
            __threadfence();
            unsigned long long total = atomicAdd(acc, 0ull);
            out[0] = (float)((double)total * (0x1p-24 / (64.0 * 1448.0)));
        }
    }
}

extern "C" void kernel_launch(void* const* d_in, const int* in_sizes, int n_in,
                              void* d_out, int out_size, void* d_ws, size_t ws_size,
                              hipStream_t stream) {
    const float* inp    = (const float*)d_in[0];
    const float* tgt    = (const float*)d_in[1];
    const int*   labels = (const int*)d_in[2];
    const float* muL    = (const float*)d_in[3];
    const float* deltaL = (const float*)d_in[4];
    const float* muR    = (const float*)d_in[5];
    const float* deltaR = (const float*)d_in[6];
    float* out = (float*)d_out;

    char* ws = (char*)d_ws;
    float*  latT = (float*)ws;                                   // 128*256*4 = 131072 B
    float*  pts3 = (float*)(ws + 131072);                        // 128*4344*4 = 2224128 B
    float4* pts4 = (float4*)(ws + 131072 + 2224128);             // 185344*16 = 2965504 B
    float*  pmin = (float*)(ws + 131072 + 2224128 + 2965504);    // 4*185344*4 = 2965504 B
    unsigned long long* acc = (unsigned long long*)(ws + 131072 + 2224128 + 2965504 + 2965504);

    hipLaunchKernelGGL(pool_kernel, dim3(2048), dim3(256), 0, stream, inp, tgt, latT, acc);
    hipLaunchKernelGGL(decode_kernel, dim3(68, 2, 2), dim3(256), 0, stream,
                       latT, muL, deltaL, muR, deltaR, labels, pts3);
    hipLaunchKernelGGL(pack_kernel, dim3((QQ * NV + 255) / 256), dim3(256), 0, stream,
                       pts3, pts4);
    hipLaunchKernelGGL(chamfer_kernel, dim3(3, 64, 8), dim3(256), 0, stream,
                       pts4, pmin);
    hipLaunchKernelGGL(combine_kernel, dim3(362), dim3(256), 0, stream, pmin, acc, out);
}

// Round 11
// 63.059 us; speedup vs baseline: 2.6440x; 1.0424x over previous
//
#include <hip/hip_runtime.h>

#define NV 1448
#define JD 4344    // 3*NV
#define CC 256
#define BB 64
#define QQ 128     // 2*BB
#define QCOLS 362  // NV/4, columns per chamfer block
#define NROW (2 * BB * NV)  // 185344 row-slots (dir x b x row)

// ---------------------------------------------------------------------------
// K1: global average pool over H*W=64 -> latT[c][q], q = t*64+b.
// Thread 0 zeroes the combine accumulator.
// ---------------------------------------------------------------------------
__global__ __launch_bounds__(256) void pool_kernel(const float* __restrict__ inp,
                                                   const float* __restrict__ tgt,
                                                   float* __restrict__ latT,
                                                   unsigned long long* __restrict__ acc) {
    int gid  = blockIdx.x * 256 + threadIdx.x;
    if (gid == 0) { acc[0] = 0ull; acc[1] = 0ull; }
    int lane = gid & 15;
    int row  = gid >> 4;                          // (t,b,c) flat, 32768 rows
    if (row >= 2 * BB * CC) return;
    int t  = row >> 14;                           // BB*CC = 16384
    int bc = row & 16383;
    const float* src = (t ? tgt : inp) + (size_t)bc * 64;
    float4 v = reinterpret_cast<const float4*>(src)[lane];
    float s = (v.x + v.y) + (v.z + v.w);
    s += __shfl_xor(s, 1);
    s += __shfl_xor(s, 2);
    s += __shfl_xor(s, 4);
    s += __shfl_xor(s, 8);
    if (lane == 0) {
        int b = bc >> 8, c = bc & 255;
        latT[c * QQ + t * BB + b] = s * (1.0f / 64.0f);
    }
}

// ---------------------------------------------------------------------------
// K2: decode GEMM v3 — 1-wave blocks for wave-granular load balance.
// grid (272 jt, 2 L, 2 qh) = 1088 blocks = 4.25/CU (prev: 272 = 1.06/CU,
// 2-round imbalance). Per block: 16 j x 64 q, 4j x 4q per thread, 8 fma
// per ds_read_b128 (same proven blocking). LDS 10KB. Barriers ~free
// (single wave).
// ---------------------------------------------------------------------------
__global__ __launch_bounds__(64, 4) void decode_kernel(const float* __restrict__ latT,
                                                       const float* __restrict__ muL,
                                                       const float* __restrict__ deltaL,
                                                       const float* __restrict__ muR,
                                                       const float* __restrict__ deltaR,
                                                       const int* __restrict__ labels,
                                                       float* __restrict__ pts3) {
    const int jt = blockIdx.x;                 // 272 tiles of 16 j
    const int L  = blockIdx.y;
    const int qh = blockIdx.z;                 // q half: 64 q's
    const float* __restrict__ delta = L ? deltaR : deltaL;
    const float* __restrict__ mu    = L ? muR : muL;
    const int j0   = jt * 16;
    const int lane = threadIdx.x;              // 0..63
    const int jl   = lane & 3;                 // 4 j-lanes x 4 j
    const int qg   = lane >> 2;                // 16 q-lanes x 4 q

    __shared__ float AsT[32][16];              // [k][j]
    __shared__ float Bs[32][64];               // [k][q]

    float acc[4][4];
#pragma unroll
    for (int u = 0; u < 4; ++u)
#pragma unroll
        for (int v = 0; v < 4; ++v) acc[u][v] = 0.f;

    const float4* latT4 = reinterpret_cast<const float4*>(latT);

    for (int kc = 0; kc < CC; kc += 32) {
        __syncthreads();
        // stage AsT: 16 j x 32 k = 128 float4, 2/thread; kq fastest for coalescing
#pragma unroll
        for (int it = 0; it < 2; ++it) {
            int idx = it * 64 + lane;
            int kq  = idx & 7;                 // 8 float4 chunks of k
            int r   = idx >> 3;                // 0..15
            int j   = j0 + r;
            float4 v = make_float4(0.f, 0.f, 0.f, 0.f);
            if (j < JD)
                v = *reinterpret_cast<const float4*>(delta + (size_t)j * CC + kc + kq * 4);
            AsT[kq * 4 + 0][r] = v.x;
            AsT[kq * 4 + 1][r] = v.y;
            AsT[kq * 4 + 2][r] = v.z;
            AsT[kq * 4 + 3][r] = v.w;
        }
        // stage Bs: 32 k x 64 q = 512 float4, 8/thread; qi fastest for coalescing
#pragma unroll
        for (int it = 0; it < 8; ++it) {
            int idx = it * 64 + lane;
            int qi  = idx & 15;                // float4 index within q-row
            int k   = idx >> 4;                // 0..31
            reinterpret_cast<float4*>(&Bs[k][0])[qi] =
                latT4[(size_t)(kc + k) * 32 + qh * 16 + qi];
        }
        __syncthreads();

#pragma unroll
        for (int k4 = 0; k4 < 32; k4 += 4) {
#pragma unroll
            for (int kk = 0; kk < 4; ++kk) {
                float4 a = *reinterpret_cast<const float4*>(&AsT[k4 + kk][jl * 4]);
                float4 b = *reinterpret_cast<const float4*>(&Bs[k4 + kk][qg * 4]);
                float av[4] = {a.x, a.y, a.z, a.w};
                float bv[4] = {b.x, b.y, b.z, b.w};
#pragma unroll
                for (int u = 0; u < 4; ++u)
#pragma unroll
                    for (int v = 0; v < 4; ++v)
                        acc[u][v] = fmaf(av[u], bv[v], acc[u][v]);
            }
        }
    }

    int j = j0 + jl * 4;
    if (j + 3 < JD) {    // JD%16 != 0: last tile partial, quad fully valid or skipped (JD%4==0)
        float4 m = *reinterpret_cast<const float4*>(mu + j);
#pragma unroll
        for (int v = 0; v < 4; ++v) {
            int q = qh * 64 + qg * 4 + v;
            int b = q & 63;
            if (labels[b] == L) {
                float4 o = make_float4(acc[0][v] + m.x, acc[1][v] + m.y,
                                       acc[2][v] + m.z, acc[3][v] + m.w);
                *reinterpret_cast<float4*>(pts3 + (size_t)q * JD + j) = o;
            }
        }
    }
}

// ---------------------------------------------------------------------------
// K3: chamfer partial row-mins, pack fused (reads pts3 directly), forced
// v_min3_f32. grid (chunk 0..2, b 0..63, z 0..7: dir=z>>2, q=z&3);
// 1536 blocks = 6/CU exact.
// ---------------------------------------------------------------------------
__global__ __launch_bounds__(256) void chamfer_kernel(const float* __restrict__ pts3,
                                                      float* __restrict__ pmin) {
    const int chunk = blockIdx.x;
    const int b     = blockIdx.y;
    const int dir   = blockIdx.z >> 2;
    const int q     = blockIdx.z & 3;
    const int qa = dir * BB + b;
    const int qb = (1 - dir) * BB + b;
    const float* __restrict__ A3 = pts3 + (size_t)qa * JD;
    const float* __restrict__ B3 = pts3 + (size_t)qb * JD + q * (QCOLS * 3);

    __shared__ float4 Bs[QCOLS];
    const int tid = threadIdx.x;
    for (int i = tid; i < QCOLS; i += 256) {
        float x = B3[3 * i], y = B3[3 * i + 1], z = B3[3 * i + 2];
        Bs[i] = make_float4(-2.f * x, -2.f * y, -2.f * z, fmaf(x, x, fmaf(y, y, z * z)));
    }
    __syncthreads();

    int r0 = chunk * 512 + tid;
    int r1 = r0 + 256;
    float a0x = 0.f, a0y = 0.f, a0z = 0.f, a0w = 0.f;
    float a1x = 0.f, a1y = 0.f, a1z = 0.f, a1w = 0.f;
    if (r0 < NV) {
        a0x = A3[3 * r0]; a0y = A3[3 * r0 + 1]; a0z = A3[3 * r0 + 2];
        a0w = fmaf(a0x, a0x, fmaf(a0y, a0y, a0z * a0z));
    }
    if (r1 < NV) {
        a1x = A3[3 * r1]; a1y = A3[3 * r1 + 1]; a1z = A3[3 * r1 + 2];
        a1w = fmaf(a1x, a1x, fmaf(a1y, a1y, a1z * a1z));
    }
    float m0 = 1e30f, m1 = 1e30f;

#pragma unroll 2
    for (int m = 0; m < QCOLS; m += 2) {
        float4 b0 = Bs[m];
        float4 b1 = Bs[m + 1];
        float d00 = fmaf(b0.x, a0x, fmaf(b0.y, a0y, fmaf(b0.z, a0z, b0.w)));
        float d01 = fmaf(b1.x, a0x, fmaf(b1.y, a0y, fmaf(b1.z, a0z, b1.w)));
        asm("v_min3_f32 %0, %0, %1, %2" : "+v"(m0) : "v"(d00), "v"(d01));
        float d10 = fmaf(b0.x, a1x, fmaf(b0.y, a1y, fmaf(b0.z, a1z, b0.w)));
        float d11 = fmaf(b1.x, a1x, fmaf(b1.y, a1y, fmaf(b1.z, a1z, b1.w)));
        asm("v_min3_f32 %0, %0, %1, %2" : "+v"(m1) : "v"(d10), "v"(d11));
    }

    size_t base = (size_t)q * NROW + (size_t)qa * NV;
    if (r0 < NV) pmin[base + r0] = m0 + a0w;
    if (r1 < NV) pmin[base + r1] = m1 + a1w;
}

// ---------------------------------------------------------------------------
// K3b: combine 4 quarter-mins, sqrt, block sums -> fixed-point atomic;
// last block writes out. 256 blocks x 724 rows exact (256*724 = 185344).
// ---------------------------------------------------------------------------
__global__ __launch_bounds__(256) void combine_kernel(const float* __restrict__ pmin,
                                                      unsigned long long* __restrict__ acc,
                                                      float* __restrict__ out) {
    const int base = blockIdx.x * 724;
    const int tid  = threadIdx.x;
    float s = 0.f;
#pragma unroll
    for (int it = 0; it < 3; ++it) {
        int idx = it * 256 + tid;
        if (idx < 724) {
            int g = base + idx;
            float v = fminf(fminf(pmin[g], pmin[g + NROW]),
                            fminf(pmin[g + 2 * NROW], pmin[g + 3 * NROW]));
            s += sqrtf(fmaxf(v, 1e-12f));
        }
    }
    s += __shfl_xor(s, 1);
    s += __shfl_xor(s, 2);
    s += __shfl_xor(s, 4);
    s += __shfl_xor(s, 8);
    s += __shfl_xor(s, 16);
    s += __shfl_xor(s, 32);
    __shared__ float wsum[4];
    if ((tid & 63) == 0) wsum[tid >> 6] = s;
    __syncthreads();
    if (tid == 0) {
        float bs = wsum[0] + wsum[1] + wsum[2] + wsum[3];
        unsigned long long qv = (unsigned long long)((double)bs * 16777216.0); // 2^24 fixed pt
        atomicAdd(acc, qv);
        __threadfence();
        unsigned long long done = atomicAdd(acc + 1, 1ull);
        if (done == 255) {
            __threadfence();
            unsigned long long total = atomicAdd(acc, 0ull);
            out[0] = (float)((double)total * (0x1p-24 / (64.0 * 1448.0)));
        }
    }
}

extern "C" void kernel_launch(void* const* d_in, const int* in_sizes, int n_in,
                              void* d_out, int out_size, void* d_ws, size_t ws_size,
                              hipStream_t stream) {
    const float* inp    = (const float*)d_in[0];
    const float* tgt    = (const float*)d_in[1];
    const int*   labels = (const int*)d_in[2];
    const float* muL    = (const float*)d_in[3];
    const float* deltaL = (const float*)d_in[4];
    const float* muR    = (const float*)d_in[5];
    const float* deltaR = (const float*)d_in[6];
    float* out = (float*)d_out;

    char* ws = (char*)d_ws;
    float* latT = (float*)ws;                                   // 128*256*4 = 131072 B
    float* pts3 = (float*)(ws + 131072);                        // 128*4344*4 = 2224128 B
    float* pmin = (float*)(ws + 131072 + 2224128);              // 4*185344*4 = 2965504 B
    unsigned long long* acc = (unsigned long long*)(ws + 131072 + 2224128 + 2965504);

    hipLaunchKernelGGL(pool_kernel, dim3(2048), dim3(256), 0, stream, inp, tgt, latT, acc);
    hipLaunchKernelGGL(decode_kernel, dim3(272, 2, 2), dim3(64), 0, stream,
                       latT, muL, deltaL, muR, deltaR, labels, pts3);
    hipLaunchKernelGGL(chamfer_kernel, dim3(3, 64, 8), dim3(256), 0, stream,
                       pts3, pmin);
    hipLaunchKernelGGL(combine_kernel, dim3(256), dim3(256), 0, stream, pmin, acc, out);
}